// Round 4
// baseline (145.814 us; speedup 1.0000x reference)
//
#include <hip/hip_runtime.h>
#include <hip/hip_bf16.h>

// einsum("btd,de->bte"): GEMM M=256000, K=512, N=16, f32 in/out.
// A = 524 MB compulsory HBM stream; floor ~85 us. R3 (direct strided frag
// loads) = 109 us = 5.0 TB/s. The MFMA A-frag layout forces each load instr
// to scatter over 16 rows x 2KB stride -> poor DRAM efficiency vs the
// contiguous patterns that hit 6.5+ TB/s on this box.
// v4: contiguous global loads (1KB/instr, lane l -> +l*16B), f32->bf16 cvt
// in regs, redistribute through a wave-private XOR-swizzled frag-ordered
// LDS buffer (8KB/wave), ds_read_b128 = one A-frag -> MFMA. Zero barriers
// (all hazards within-wave; DS completes in order + compiler lgkmcnt).
// B-frags register-resident (R2 build, verified absmax 0.5).

#define D_IN   512
#define D_OUT  16
#define NROWS  (128 * 2000)     // 256000
#define BLOCK  256
#define GRID   1000             // 4000 waves x 4 tiles x 16 rows = 256000

typedef short  short8 __attribute__((ext_vector_type(8)));
typedef float  f32x4  __attribute__((ext_vector_type(4)));

__device__ __forceinline__ unsigned int cvt2(float lo, float hi) {
    union { __hip_bfloat162 h; unsigned int u; } c;
    c.h = __float22bfloat162_rn(make_float2(lo, hi));
    return c.u;
}

__global__ __launch_bounds__(BLOCK, 4) void ts_mm_v4(
    const float* __restrict__ A,   // [NROWS, D_IN]
    const float* __restrict__ W,   // [D_IN, D_OUT]
    float* __restrict__ O)         // [NROWS, D_OUT]
{
    // Wave-private half-tile staging: 16 rows x 256 k x bf16 = 8KB per wave.
    // Layout: entry m = kt_local*4+g (0..31) x row e (0..15) -> 16B frag at
    // byte m*256 + (e*16 ^ ((m&7)<<4)).  XOR spreads banks: b64 writes land
    // 4 lanes/slot (optimal), b128 reads 8 lanes/slot (optimal).
    __shared__ __align__(16) char sbuf[4][8192];

    const int lane = threadIdx.x & 63;
    const int wid  = threadIdx.x >> 6;
    const int e    = lane & 15;          // frag row (A) / out col (B)
    const int g    = lane >> 4;          // k-group 0..3
    const int tile0 = (blockIdx.x * 4 + wid) * 4;

    // ---- B fragments in registers: bfrag[kt] = W[kt*32 + g*8 .. +7][e] ----
    short8 bfrag[16];
#pragma unroll
    for (int kt = 0; kt < 16; ++kt) {
        const float* wp = W + (size_t)(kt * 32 + g * 8) * D_OUT + e;
        union { unsigned int u[4]; short8 s; } c;
        c.u[0] = cvt2(wp[0 * 16], wp[1 * 16]);
        c.u[1] = cvt2(wp[2 * 16], wp[3 * 16]);
        c.u[2] = cvt2(wp[4 * 16], wp[5 * 16]);
        c.u[3] = cvt2(wp[6 * 16], wp[7 * 16]);
        bfrag[kt] = c.s;
    }

    // Per-lane staging-write address: lane l holds row j, k-local l*4..l*4+3
    // -> entry m = l>>1, low/high 8B = l&1.
    char* const wbase = sbuf[wid] + (lane >> 1) * 256 + (lane & 1) * 8;
    const int   wxor  = ((lane >> 1) & 7) << 4;
    const char* const rbase = sbuf[wid];

#pragma unroll 1
    for (int i = 0; i < 4; ++i) {
        const int tile = tile0 + i;
        f32x4 acc = {0.f, 0.f, 0.f, 0.f};

#pragma unroll 1
        for (int h = 0; h < 2; ++h) {
            // Contiguous f32 source for this K-half: instr j covers row j's
            // 1KB half; lane l at +l*16B (perfect 1KB/instr coalescing).
            const float* ap = A + (size_t)tile * 16 * D_IN + h * 256 + lane * 4;

#pragma unroll 1
            for (int jj = 0; jj < 2; ++jj) {
                float4 v[8];
#pragma unroll
                for (int j = 0; j < 8; ++j)
                    v[j] = *(const float4*)(ap + (size_t)(jj * 8 + j) * D_IN);
#pragma unroll
                for (int j = 0; j < 8; ++j) {
                    unsigned long long p =
                        (unsigned long long)cvt2(v[j].x, v[j].y) |
                        ((unsigned long long)cvt2(v[j].z, v[j].w) << 32);
                    *(unsigned long long*)(wbase + (((jj * 8 + j) * 16) ^ wxor)) = p;
                }
            }

            // Consume: one ds_read_b128 per kt = the lane's A-frag.
#pragma unroll
            for (int kt = 0; kt < 8; ++kt) {
                const int m = kt * 4 + g;
                short8 af = *(const short8*)(rbase + m * 256 + ((e * 16) ^ ((m & 7) << 4)));
                acc = __builtin_amdgcn_mfma_f32_16x16x32_bf16(
                          af, bfrag[h * 8 + kt], acc, 0, 0, 0);
            }
        }

        // D: lane holds rows g*4+r (r=0..3), col e; 64B contiguous per
        // 16-lane group per store.
        float* op = O + (size_t)tile * (16 * D_OUT) + (size_t)(g * 4) * D_OUT + e;
        op[0 * D_OUT] = acc[0];
        op[1 * D_OUT] = acc[1];
        op[2 * D_OUT] = acc[2];
        op[3 * D_OUT] = acc[3];
    }
}

extern "C" void kernel_launch(void* const* d_in, const int* in_sizes, int n_in,
                              void* d_out, int out_size, void* d_ws, size_t ws_size,
                              hipStream_t stream) {
    const float* A = (const float*)d_in[0];   // data    [128, 2000, 512]
    const float* W = (const float*)d_in[1];   // weights [512, 16]
    float*       O = (float*)d_out;           // out     [128, 2000, 16]

    ts_mm_v4<<<dim3(GRID), dim3(BLOCK), 0, stream>>>(A, W, O);
}

// Round 5
// 136.257 us; speedup vs baseline: 1.0701x; 1.0701x over previous
//
#include <hip/hip_runtime.h>
#include <hip/hip_bf16.h>

// einsum("btd,de->bte"): GEMM M=256000, K=512, N=16, f32 in/out.
// A = 524 MB compulsory HBM stream; floor ~85 us.
// R3 = 109 us (5.0 TB/s) at 4 waves/SIMD. v4 (LDS redistribution) = 146 us:
// serialized load->cvt->write->read->mfma chain, invalid test of the
// DRAM-pattern theory.
// v5: occupancy experiment. Same A access pattern as R3, but B-frags in LDS
// (frees 64 VGPRs) and no explicit register batch -> fits 64 VGPR ->
// __launch_bounds__(256,8) = 8 waves/SIMD, grid 2000 x 2 tiles/wave = 8000
// resident waves. Compiler prefetches the unrolled kt-loop as deep as the
// budget allows. Discriminates latency-bound (-> ~95 us) vs pattern-bound
// (-> unchanged).

#define D_IN   512
#define D_OUT  16
#define NROWS  (128 * 2000)     // 256000
#define BLOCK  256
#define GRID   2000             // 8000 waves x 2 tiles = 16000 row-tiles

typedef short  short8 __attribute__((ext_vector_type(8)));
typedef float  f32x4  __attribute__((ext_vector_type(4)));

__device__ __forceinline__ unsigned int cvt2(float lo, float hi) {
    union { __hip_bfloat162 h; unsigned int u; } c;
    c.h = __float22bfloat162_rn(make_float2(lo, hi));
    return c.u;
}

__global__ __launch_bounds__(BLOCK, 8) void ts_mm_v5(
    const float* __restrict__ A,   // [NROWS, D_IN]
    const float* __restrict__ W,   // [D_IN, D_OUT]
    float* __restrict__ O)         // [NROWS, D_OUT]
{
    // B-fragment table (v3-verified): entry (kt*4+g)*16+e is lane (e,g)'s
    // 16B B-frag for k-tile kt. 1024 x 16B = 16 KB.
    __shared__ short8 Wp[16 * 4 * 16];

    {
        const int tid = threadIdx.x;
#pragma unroll
        for (int it = 0; it < 4; ++it) {
            const int id = tid + it * 256;
            const int kt = id >> 6;
            const int gg = (id >> 4) & 3;
            const int ee = id & 15;
            const float* wp = W + (size_t)(kt * 32 + gg * 8) * D_OUT + ee;
            union { unsigned int u[4]; short8 s; } c;
            c.u[0] = cvt2(wp[0 * 16], wp[1 * 16]);
            c.u[1] = cvt2(wp[2 * 16], wp[3 * 16]);
            c.u[2] = cvt2(wp[4 * 16], wp[5 * 16]);
            c.u[3] = cvt2(wp[6 * 16], wp[7 * 16]);
            Wp[id] = c.s;
        }
    }
    __syncthreads();

    const int lane  = threadIdx.x & 63;
    const int wid   = threadIdx.x >> 6;
    const int e     = lane & 15;          // frag row (A) / out col (B)
    const int g     = lane >> 4;          // k-group 0..3
    const int tile0 = (blockIdx.x * 4 + wid) * 2;

#pragma unroll 1
    for (int i = 0; i < 2; ++i) {
        const int tile = tile0 + i;
        const float* ap = A + ((size_t)tile * 16 + e) * D_IN + g * 8;

        f32x4 acc = {0.f, 0.f, 0.f, 0.f};

        // Fully unrolled: compiler hoists loads as deep as 64-VGPR allows;
        // 8 waves/SIMD provide the TLP to cover the rest.
#pragma unroll
        for (int kt = 0; kt < 16; ++kt) {
            float4 x = *(const float4*)(ap + kt * 32);
            float4 y = *(const float4*)(ap + kt * 32 + 4);
            union { unsigned int u[4]; short8 s; } c;
            c.u[0] = cvt2(x.x, x.y);
            c.u[1] = cvt2(x.z, x.w);
            c.u[2] = cvt2(y.x, y.y);
            c.u[3] = cvt2(y.z, y.w);
            acc = __builtin_amdgcn_mfma_f32_16x16x32_bf16(
                      c.s, Wp[kt * 64 + g * 16 + e], acc, 0, 0, 0);
        }

        float* op = O + (size_t)tile * (16 * D_OUT) + (size_t)(g * 4) * D_OUT + e;
        op[0 * D_OUT] = acc[0];
        op[1 * D_OUT] = acc[1];
        op[2 * D_OUT] = acc[2];
        op[3 * D_OUT] = acc[3];
    }
}

extern "C" void kernel_launch(void* const* d_in, const int* in_sizes, int n_in,
                              void* d_out, int out_size, void* d_ws, size_t ws_size,
                              hipStream_t stream) {
    const float* A = (const float*)d_in[0];   // data    [128, 2000, 512]
    const float* W = (const float*)d_in[1];   // weights [512, 16]
    float*       O = (float*)d_out;           // out     [128, 2000, 16]

    ts_mm_v5<<<dim3(GRID), dim3(BLOCK), 0, stream>>>(A, W, O);
}

// Round 6
// 105.706 us; speedup vs baseline: 1.3794x; 1.2890x over previous
//
#include <hip/hip_runtime.h>
#include <hip/hip_bf16.h>

// einsum("btd,de->bte"): GEMM M=256000, K=512, N=16, f32 in/out.
// A = 524 MB compulsory HBM stream; floor ~85 us. History: R1 134 (VALU),
// R2 115, R3 109 (frag-pattern loads, 5.0 TB/s), v4 146 (serialized LDS),
// v5 136 (occupancy up / ILP down). All >=109 kernels share the frag-layout
// A-pattern: each instr scatters 16B x 64 lanes over 16 rows x 2KB stride.
// v6 tests the DRAM-pattern hypothesis cleanly: block tile = 16 full rows
// = one contiguous 32 KB chunk streamed via global_load_lds (1KB/instr,
// fill-kernel pattern), double-buffered. LDS stays linear; the read-side
// bank swizzle is obtained by pre-swizzling the GLOBAL source address
// (involution L ^= ((row&7)<<4), rule m231/m201). Waves split K 4-ways,
// partial C reduced via 4KB LDS buffer. 68 KB LDS -> 2 blocks/CU ->
// 64 KB/CU of A permanently in flight.

#define D_IN   512
#define D_OUT  16
#define NROWS  (128 * 2000)       // 256000 rows -> 16000 tiles of 16 rows
#define BLOCK  256
#define TPB    4                  // tiles per block
#define GRID   (16000 / TPB)      // 4000 blocks

typedef short  short8 __attribute__((ext_vector_type(8)));
typedef float  f32x4  __attribute__((ext_vector_type(4)));

__device__ __forceinline__ unsigned int cvt2(float lo, float hi) {
    union { __hip_bfloat162 h; unsigned int u; } c;
    c.h = __float22bfloat162_rn(make_float2(lo, hi));
    return c.u;
}

__global__ __launch_bounds__(BLOCK, 2) void ts_mm_v6(
    const float* __restrict__ A,   // [NROWS, D_IN]
    const float* __restrict__ W,   // [D_IN, D_OUT]
    float* __restrict__ O)         // [NROWS, D_OUT]
{
    // Double-buffered A tile: 16 rows x 512 f32 = 32 KB, linear layout,
    // data pre-swizzled at the global source so frag reads are bank-clean.
    __shared__ __align__(16) char buf[2][32768];
    // Cross-wave K-split partials: [wave][row][col] f32 = 4 KB.
    __shared__ float part[4][16][16];

    const int lane = threadIdx.x & 63;
    const int wid  = threadIdx.x >> 6;     // wave 0..3 = K-quarter owner
    const int e    = lane & 15;            // frag row (A) / out col (B)
    const int g    = lane >> 4;            // k-subgroup 0..3
    const int tid  = threadIdx.x;
    const int sw   = (e & 7) << 4;         // read-side XOR swizzle

    // ---- B fragments (registers): wave w needs kt = w*4 .. w*4+3 ----
    short8 bfrag[4];
#pragma unroll
    for (int j = 0; j < 4; ++j) {
        const int kt = wid * 4 + j;
        const float* wp = W + (size_t)(kt * 32 + g * 8) * D_OUT + e;
        union { unsigned int u[4]; short8 s; } c;
        c.u[0] = cvt2(wp[0 * 16], wp[1 * 16]);
        c.u[1] = cvt2(wp[2 * 16], wp[3 * 16]);
        c.u[2] = cvt2(wp[4 * 16], wp[5 * 16]);
        c.u[3] = cvt2(wp[6 * 16], wp[7 * 16]);
        bfrag[j] = c.s;
    }

    const int tile0 = blockIdx.x * TPB;

    // Stage one 32 KB tile: 8 x global_load_lds_dwordx4 per thread.
    // LDS linear; source pre-swizzled (involution) so that the frag read
    // at raw byte R reads LDS[R ^ ((row&7)<<4)] and gets logical byte R.
    auto stage = [&](int tile, int bsel) {
        const char* abase = (const char*)A + (size_t)tile * 32768;
#pragma unroll
        for (int it = 0; it < 8; ++it) {
            const int L = it * 4096 + wid * 1024 + lane * 16;   // lds landing byte
            const int S = L ^ (((L >> 11) & 7) << 4);           // source byte
            __builtin_amdgcn_global_load_lds(
                (const __attribute__((address_space(1))) void*)(abase + S),
                (__attribute__((address_space(3))) void*)(&buf[bsel][it * 4096 + wid * 1024]),
                16, 0, 0);
        }
    };

    stage(tile0, 0);
    __syncthreads();

#pragma unroll 1
    for (int t = 0; t < TPB; ++t) {
        const int cur  = t & 1;
        const int tile = tile0 + t;

        if (t + 1 < TPB) stage(tile + 1, cur ^ 1);

        // ---- Partial C over this wave's K-quarter: 8 ds_read_b128 + 4 MFMA ----
        const char* rb = buf[cur];
        f32x4 acc = {0.f, 0.f, 0.f, 0.f};
#pragma unroll
        for (int j = 0; j < 4; ++j) {
            const int kt = wid * 4 + j;
            const int ra = e * 2048 + kt * 128 + g * 32;
            f32x4 lo = *(const f32x4*)(rb + (ra ^ sw));
            f32x4 hi = *(const f32x4*)(rb + ((ra + 16) ^ sw));
            union { unsigned int u[4]; short8 s; } c;
            c.u[0] = cvt2(lo[0], lo[1]);
            c.u[1] = cvt2(lo[2], lo[3]);
            c.u[2] = cvt2(hi[0], hi[1]);
            c.u[3] = cvt2(hi[2], hi[3]);
            acc = __builtin_amdgcn_mfma_f32_16x16x32_bf16(c.s, bfrag[j], acc, 0, 0, 0);
        }

        // lane holds rows g*4+r (r=0..3), col e of this wave's partial.
        part[wid][g * 4 + 0][e] = acc[0];
        part[wid][g * 4 + 1][e] = acc[1];
        part[wid][g * 4 + 2][e] = acc[2];
        part[wid][g * 4 + 3][e] = acc[3];

        __syncthreads();   // partials visible (also drains prefetch vmcnt)

        // ---- Reduce 4 K-quarters, store 1 KB contiguous ----
        {
            const int r = tid >> 4, c = tid & 15;
            float s = part[0][r][c] + part[1][r][c] + part[2][r][c] + part[3][r][c];
            O[(size_t)tile * 256 + tid] = s;
        }

        __syncthreads();   // part[] reusable; buffers swappable
    }
}

extern "C" void kernel_launch(void* const* d_in, const int* in_sizes, int n_in,
                              void* d_out, int out_size, void* d_ws, size_t ws_size,
                              hipStream_t stream) {
    const float* A = (const float*)d_in[0];   // data    [128, 2000, 512]
    const float* W = (const float*)d_in[1];   // weights [512, 16]
    float*       O = (float*)d_out;           // out     [128, 2000, 16]

    ts_mm_v6<<<dim3(GRID), dim3(BLOCK), 0, stream>>>(A, W, O);
}

// Round 7
// 104.083 us; speedup vs baseline: 1.4009x; 1.0156x over previous
//
#include <hip/hip_runtime.h>
#include <hip/hip_bf16.h>

// einsum("btd,de->bte"): GEMM M=256000, K=512, N=16, f32 in/out.
// A = 524 MB compulsory HBM stream; floor ~85 us. R3 109 (frag-pattern),
// v6 105.7 (contiguous global_load_lds staging, __syncthreads). v6's flaw:
// __syncthreads emits s_waitcnt vmcnt(0) -> the tile t+1 prefetch issued
// just before the barrier is drained immediately; zero pipelining.
// v7 = v6 + T4: raw s_barrier + counted s_waitcnt vmcnt(8) so the next
// tile's 32 KB stays in flight across the barrier; DS-phase barrier uses
// lgkmcnt(0) only. Everything else identical to v6 (verified absmax 0.5).

#define D_IN   512
#define D_OUT  16
#define NROWS  (128 * 2000)       // 256000 rows -> 16000 tiles of 16 rows
#define BLOCK  256
#define TPB    4                  // tiles per block
#define GRID   (16000 / TPB)      // 4000 blocks

typedef short  short8 __attribute__((ext_vector_type(8)));
typedef float  f32x4  __attribute__((ext_vector_type(4)));

__device__ __forceinline__ unsigned int cvt2(float lo, float hi) {
    union { __hip_bfloat162 h; unsigned int u; } c;
    c.h = __float22bfloat162_rn(make_float2(lo, hi));
    return c.u;
}

__global__ __launch_bounds__(BLOCK, 2) void ts_mm_v7(
    const float* __restrict__ A,   // [NROWS, D_IN]
    const float* __restrict__ W,   // [D_IN, D_OUT]
    float* __restrict__ O)         // [NROWS, D_OUT]
{
    // Double-buffered A tile: 16 rows x 512 f32 = 32 KB, linear layout,
    // source pre-swizzled so frag-layout ds_reads are bank-clean.
    __shared__ __align__(16) char buf[2][32768];
    // Cross-wave K-split partials: [wave][row][col] f32 = 4 KB.
    __shared__ float part[4][16][16];

    const int lane = threadIdx.x & 63;
    const int wid  = threadIdx.x >> 6;     // wave 0..3 = K-quarter owner
    const int e    = lane & 15;            // frag row (A) / out col (B)
    const int g    = lane >> 4;            // k-subgroup 0..3
    const int tid  = threadIdx.x;
    const int sw   = (e & 7) << 4;         // read-side XOR swizzle

    // ---- B fragments (registers): wave w covers kt = w*4 .. w*4+3 ----
    short8 bfrag[4];
#pragma unroll
    for (int j = 0; j < 4; ++j) {
        const int kt = wid * 4 + j;
        const float* wp = W + (size_t)(kt * 32 + g * 8) * D_OUT + e;
        union { unsigned int u[4]; short8 s; } c;
        c.u[0] = cvt2(wp[0 * 16], wp[1 * 16]);
        c.u[1] = cvt2(wp[2 * 16], wp[3 * 16]);
        c.u[2] = cvt2(wp[4 * 16], wp[5 * 16]);
        c.u[3] = cvt2(wp[6 * 16], wp[7 * 16]);
        bfrag[j] = c.s;
    }

    const int tile0 = blockIdx.x * TPB;

    // Stage one 32 KB tile: 8 x global_load_lds_dwordx4 per thread.
    // LDS dest linear (gload_lds requirement); global source pre-swizzled
    // with the same involution the reader applies (rule #21).
    auto stage = [&](int tile, int bsel) {
        const char* abase = (const char*)A + (size_t)tile * 32768;
#pragma unroll
        for (int it = 0; it < 8; ++it) {
            const int L = it * 4096 + wid * 1024 + lane * 16;   // lds landing byte
            const int S = L ^ (((L >> 11) & 7) << 4);           // source byte
            __builtin_amdgcn_global_load_lds(
                (const __attribute__((address_space(1))) void*)(abase + S),
                (__attribute__((address_space(3))) void*)(&buf[bsel][it * 4096 + wid * 1024]),
                16, 0, 0);
        }
    };

    stage(tile0, 0);

#pragma unroll 1
    for (int t = 0; t < TPB; ++t) {
        const int cur  = t & 1;
        const int tile = tile0 + t;

        if (t + 1 < TPB) {
            stage(tile + 1, cur ^ 1);
            // Wait only tile t's 8 loads (+ older O-store); keep the 8 new
            // prefetch loads in flight across the barrier.
            asm volatile("s_waitcnt vmcnt(8)" ::: "memory");
        } else {
            asm volatile("s_waitcnt vmcnt(0)" ::: "memory");
        }
        __builtin_amdgcn_sched_barrier(0);
        __builtin_amdgcn_s_barrier();

        // ---- Partial C over this wave's K-quarter: 8 ds_read_b128 + 4 MFMA ----
        const char* rb = buf[cur];
        f32x4 acc = {0.f, 0.f, 0.f, 0.f};
#pragma unroll
        for (int j = 0; j < 4; ++j) {
            const int kt = wid * 4 + j;
            const int ra = e * 2048 + kt * 128 + g * 32;
            f32x4 lo = *(const f32x4*)(rb + (ra ^ sw));
            f32x4 hi = *(const f32x4*)(rb + ((ra + 16) ^ sw));
            union { unsigned int u[4]; short8 s; } c;
            c.u[0] = cvt2(lo[0], lo[1]);
            c.u[1] = cvt2(lo[2], lo[3]);
            c.u[2] = cvt2(hi[0], hi[1]);
            c.u[3] = cvt2(hi[2], hi[3]);
            acc = __builtin_amdgcn_mfma_f32_16x16x32_bf16(c.s, bfrag[j], acc, 0, 0, 0);
        }

        // lane holds rows g*4+r (r=0..3), col e of this wave's partial.
        part[wid][g * 4 + 0][e] = acc[0];
        part[wid][g * 4 + 1][e] = acc[1];
        part[wid][g * 4 + 2][e] = acc[2];
        part[wid][g * 4 + 3][e] = acc[3];

        // DS-only barrier: make partials visible without draining vmcnt.
        asm volatile("s_waitcnt lgkmcnt(0)" ::: "memory");
        __builtin_amdgcn_sched_barrier(0);
        __builtin_amdgcn_s_barrier();

        // ---- Reduce 4 K-quarters, store 1 KB contiguous ----
        {
            const int r = tid >> 4, c = tid & 15;
            float s = part[0][r][c] + part[1][r][c] + part[2][r][c] + part[3][r][c];
            O[(size_t)tile * 256 + tid] = s;
        }
        // part[] reuse + buf-read-completion for the next iteration are
        // protected by the next iteration's top barrier (reduce reads are
        // consumed before the store issues; all waves pass that barrier
        // after their reads).
    }
}

extern "C" void kernel_launch(void* const* d_in, const int* in_sizes, int n_in,
                              void* d_out, int out_size, void* d_ws, size_t ws_size,
                              hipStream_t stream) {
    const float* A = (const float*)d_in[0];   // data    [128, 2000, 512]
    const float* W = (const float*)d_in[1];   // weights [512, 16]
    float*       O = (float*)d_out;           // out     [128, 2000, 16]

    ts_mm_v7<<<dim3(GRID), dim3(BLOCK), 0, stream>>>(A, W, O);
}